// Round 14
// baseline (32.291 us; speedup 1.0000x reference)
//
#include <hip/hip_runtime.h>

#define HH 128
#define WW 192
#define HW (HH * WW)
#define PXI (HH * WW)          // 24576 px per instance

typedef float f32x4 __attribute__((ext_vector_type(4)));
typedef __fp16 h2 __attribute__((ext_vector_type(2)));

__device__ __forceinline__ float relu(float v) { return fmaxf(v, 0.0f); }
__device__ __forceinline__ float fdot2(h2 a, h2 b, float c) {
    return __builtin_amdgcn_fdot2(a, b, c, false);
}
__device__ __forceinline__ h2 pkrtz(float a, float b) {
    return __builtin_amdgcn_cvt_pkrtz(a, b);
}

// LDS packed-weight layout (R11):
//   sWp (h2): [0..31] w0feat o*4+p=(w0[o][2+2p],w0[o][3+2p])
//             [32..63] w1 32+o*4+p=(w1[o][2p],w1[o][2p+1])
//             [64..67] w2 64+p=(w2[2p],w2[2p+1])
//   sF (f32): [0..7] w0x [8..15] w0y [16..23] b0 [24..31] b1 [32] b2

// ---------------- Kernel A: logits -> d_ws (128 x 24576 fp32) ----------------
__global__ __launch_bounds__(512) void logits_kernel(
    const float* __restrict__ mask_feats,
    const float* __restrict__ params,
    const float* __restrict__ locs,
    const float* __restrict__ soi,
    const int*   __restrict__ im_inds,
    const int*   __restrict__ fpn_levels,
    const int*   __restrict__ stride_p,
    float*       __restrict__ ws)
{
    const int tid = threadIdx.x;
    const int bx  = blockIdx.x;       // 0..11 (2048 px each)
    const int n   = blockIdx.y;       // instance

    __shared__ h2    sWp[68];
    __shared__ float sF[33];

    // stage weights (fp16 packs for matmul, fp32 coords/biases)
    if (tid < 169) {
        float v = params[(size_t)n * 169 + tid];
        __fp16* sWh = reinterpret_cast<__fp16*>(sWp);
        if (tid < 80) {
            int o = tid / 10, k = tid - o * 10;
            if (k == 0)      sF[o] = v;
            else if (k == 1) sF[8 + o] = v;
            else { int f = k - 2; sWh[(o * 4 + (f >> 1)) * 2 + (f & 1)] = (__fp16)v; }
        } else if (tid < 144) {
            int t = tid - 80, o = t >> 3, i = t & 7;
            sWh[(32 + o * 4 + (i >> 1)) * 2 + (i & 1)] = (__fp16)v;
        } else if (tid < 152) {
            int o = tid - 144;
            sWh[(64 + (o >> 1)) * 2 + (o & 1)] = (__fp16)v;
        } else if (tid < 160) sF[16 + (tid - 152)] = v;
        else if (tid < 168)   sF[24 + (tid - 160)] = v;
        else                  sF[32] = v;
    }

    const int   stride = *stride_p;             // 8
    const float half_s = 0.5f * (float)stride;  // 4.0
    const float locx = locs[2 * n + 0];
    const float locy = locs[2 * n + 1];
    const float inv  = 1.0f / soi[fpn_levels[n]];
    const float* fb  = mask_feats + (size_t)im_inds[n] * 8 * HW;

    // 4 contiguous px per thread (same row: 192 % 4 == 0); loads pre-barrier
    const int px  = bx * 2048 + tid * 4;
    const int row = px / WW;
    const int col = px - row * WW;
    const float* fp = fb + px;

    f32x4 xv[8];
    #pragma unroll
    for (int ch = 0; ch < 8; ++ch)
        xv[ch] = *reinterpret_cast<const f32x4*>(fp + ch * HW);

    __syncthreads();

    const float rxd = -(float)stride * inv;
    float rx[4];
    rx[0] = (locx - (float)(col * stride) - half_s) * inv;
    rx[1] = rx[0] + rxd; rx[2] = rx[1] + rxd; rx[3] = rx[2] + rxd;
    const float ry = (locy - (float)(row * stride) - half_s) * inv;

    h2 xp[4][4];
    #pragma unroll
    for (int p = 0; p < 4; ++p)
        #pragma unroll
        for (int j = 0; j < 4; ++j)
            xp[p][j] = pkrtz(xv[2 * p][j], xv[2 * p + 1][j]);

    float h[8][4];
    #pragma unroll
    for (int o = 0; o < 8; ++o) {
        const h2 w0 = sWp[o * 4 + 0], w1 = sWp[o * 4 + 1],
                 w2 = sWp[o * 4 + 2], w3 = sWp[o * 4 + 3];
        float tO = fmaf(sF[8 + o], ry, sF[16 + o]);
        float wx = sF[o];
        #pragma unroll
        for (int j = 0; j < 4; ++j) {
            float acc = fmaf(wx, rx[j], tO);
            acc = fdot2(w0, xp[0][j], acc);
            acc = fdot2(w1, xp[1][j], acc);
            acc = fdot2(w2, xp[2][j], acc);
            acc = fdot2(w3, xp[3][j], acc);
            h[o][j] = acc;
        }
    }
    h2 hp[4][4];
    #pragma unroll
    for (int p = 0; p < 4; ++p)
        #pragma unroll
        for (int j = 0; j < 4; ++j)
            hp[p][j] = pkrtz(relu(h[2 * p][j]), relu(h[2 * p + 1][j]));

    float a[8][4];
    #pragma unroll
    for (int o = 0; o < 8; ++o) {
        const h2 w0 = sWp[32 + o * 4 + 0], w1 = sWp[32 + o * 4 + 1],
                 w2 = sWp[32 + o * 4 + 2], w3 = sWp[32 + o * 4 + 3];
        float b1 = sF[24 + o];
        #pragma unroll
        for (int j = 0; j < 4; ++j) {
            float acc = b1;
            acc = fdot2(w0, hp[0][j], acc);
            acc = fdot2(w1, hp[1][j], acc);
            acc = fdot2(w2, hp[2][j], acc);
            acc = fdot2(w3, hp[3][j], acc);
            a[o][j] = acc;
        }
    }
    const h2 v0 = sWp[64], v1 = sWp[65], v2 = sWp[66], v3 = sWp[67];
    const float b2v = sF[32];
    f32x4 lg;
    #pragma unroll
    for (int j = 0; j < 4; ++j) {
        h2 a0 = pkrtz(relu(a[0][j]), relu(a[1][j]));
        h2 a1 = pkrtz(relu(a[2][j]), relu(a[3][j]));
        h2 a2 = pkrtz(relu(a[4][j]), relu(a[5][j]));
        h2 a3 = pkrtz(relu(a[6][j]), relu(a[7][j]));
        float l = b2v;
        l = fdot2(v0, a0, l);
        l = fdot2(v1, a1, l);
        l = fdot2(v2, a2, l);
        l = fdot2(v3, a3, l);
        lg[j] = l;
    }
    *reinterpret_cast<f32x4*>(ws + (size_t)n * PXI + px) = lg;
}

// ---------------- Kernel B: upsample ws -> out (pure streaming) ----------------
__global__ __launch_bounds__(256) void upsample_kernel(
    const float* __restrict__ ws,    // (128, 128, 192) logits
    float*       __restrict__ out)   // (128, 256, 384)
{
    const int tid = threadIdx.x;
    const int g0  = blockIdx.x * 1024 + tid;

    #pragma unroll
    for (int k = 0; k < 4; ++k) {
        const int g   = g0 + k * 256;          // global float4 index, 0..3145727
        const int yg  = g / 96;                // global out row (n*256 + y)
        const int f4c = g - yg * 96;           // float4 col chunk 0..95
        const int n   = yg >> 8;
        const int y   = yg & 255;

        const int iy = y - 1;
        const int rb = iy >> 1;                // -1 only when y==0
        const int fy = iy & 1;
        const float wy0 = fy ? 0.5f : 1.0f;
        const float wy1 = fy ? 0.5f : 0.0f;
        const int r1 = max(rb, 0);
        const int r2 = rb + fy;                // in [0,127]; y==0 -> r2=0

        const float* La = ws + (size_t)n * PXI + r1 * WW;
        const float* Lb = ws + (size_t)n * PXI + r2 * WW;

        const int m0 = 2 * f4c - 1;
        const int mc = max(m0, 0);
        float t0 = fmaf(wy1, Lb[mc],     wy0 * La[mc]);
        float t1 = fmaf(wy1, Lb[m0 + 1], wy0 * La[m0 + 1]);
        float t2 = fmaf(wy1, Lb[m0 + 2], wy0 * La[m0 + 2]);

        f32x4 o4;
        o4.x = 0.5f * (t0 + t1);
        o4.y = t1;
        o4.z = 0.5f * (t1 + t2);
        o4.w = t2;
        __builtin_nontemporal_store(o4,
            reinterpret_cast<f32x4*>(out + (size_t)yg * 384 + 4 * f4c));
    }
}

extern "C" void kernel_launch(void* const* d_in, const int* in_sizes, int n_in,
                              void* d_out, int out_size, void* d_ws, size_t ws_size,
                              hipStream_t stream) {
    const float* mask_feats = (const float*)d_in[0];
    const float* params     = (const float*)d_in[1];
    const float* locs       = (const float*)d_in[2];
    const float* soi        = (const float*)d_in[3];
    const int*   im_inds    = (const int*)d_in[4];
    const int*   fpn_levels = (const int*)d_in[5];
    const int*   stride_p   = (const int*)d_in[6];
    float* out = (float*)d_out;
    float* ws  = (float*)d_ws;   // needs 128*24576*4 = 12.6 MB

    dim3 gridA(12, 128);
    logits_kernel<<<gridA, dim3(512), 0, stream>>>(
        mask_feats, params, locs, soi, im_inds, fpn_levels, stride_p, ws);

    // 128 inst * 256 rows * 96 float4 = 3,145,728 f4 = 3072 blocks * 1024
    upsample_kernel<<<dim3(3072), dim3(256), 0, stream>>>(ws, out);
}